// Round 1
// baseline (215.042 us; speedup 1.0000x reference)
//
#include <hip/hip_runtime.h>
#include <hip/hip_bf16.h>

// SirenLinear: out[b,r] = sum_c x[b,c] * W[r,c] + bias[r]
//   W[r,c] = b3 + h2 . W3,  h2 = sin(30*(W2 h1 + b2)),  h1 = sin(30*(W1 e + b1))
//
// Round-7 changes:
//  * Launch graph restructured around the true dependency DAG:
//      tables (tiny) -> [cast || siren_w] merged, 1-in-9 interleaved -> gemm.
//    cast (HBM-bound) and siren_w (VALU/MFMA-bound) are independent; putting
//    them in ONE launch with interleaved block ids co-schedules them on every
//    CU (m114: separate pipes overlap at ~max, not sum).
//  * gemm: double-buffered LDS (2x32KB) with prefetch-before-compute and ONE
//    barrier per K-tile (T3 minimum-2-phase). The old stage->drain->compute
//    loop exposed full global->LDS latency 16x with all waves parked.

typedef __attribute__((ext_vector_type(8))) short bf16x8;
typedef __attribute__((ext_vector_type(4))) float f32x4;

#define SIN_SCALE 4.77464829275686f   // 30 / (2*pi)

__device__ __forceinline__ unsigned short f2bf(float f) {
    union { float f; unsigned u; } v; v.f = f;
    unsigned r = v.u + 0x7fffu + ((v.u >> 16) & 1u);   // RNE
    return (unsigned short)(r >> 16);
}

// pack 2 floats -> 2 bf16 by truncation (cheap; RNE kept for final store)
__device__ __forceinline__ unsigned pktrunc(float a, float b) {
    union { float f; unsigned u; } x, y; x.f = a; y.f = b;
    return (x.u >> 16) | (y.u & 0xffff0000u);
}

// sin(2*pi*x) -- raw v_sin_f32, valid |x| <= 256 revs (here |x| <= ~8.3)
__device__ __forceinline__ float sinrev(float x) {
    return __builtin_amdgcn_sinf(x);
}

// butterfly add over lane^m (bitmode ds_swizzle)
template <int OFF>
__device__ __forceinline__ float swz_add(float v) {
    return v + __int_as_float(__builtin_amdgcn_ds_swizzle(__float_as_int(v), OFF));
}

__device__ __forceinline__ void async_ld16(const void* g, void* l) {
    __builtin_amdgcn_global_load_lds(
        (__attribute__((address_space(1))) void*)g,
        (__attribute__((address_space(3))) void*)l, 16, 0, 0);
}

// ---------------- stage 0: layer-1 separable tables ----------------
// Zrow[r][j] = S*(W1[j,:].e(r,0)+b1[j]);  Zcol[c][j] = S*(W1[j,:].(e(0,c)-e(0,0)))
__global__ __launch_bounds__(256) void tables_kernel(
        const float* __restrict__ ec,
        const float* __restrict__ W1, const float* __restrict__ b1,
        float* __restrict__ Zrow, float* __restrict__ Zcol) {
    int idx = blockIdx.x * 256 + threadIdx.x;    // 0..131071
    int j = idx & 63;
    int t = idx >> 6;                            // 0..2047
    const float* wr = W1 + j * 18;
    if (t < 1024) {
        const float* pe = ec + (long)t * 1024 * 18;   // point (r=t, c=0)
        float z = b1[j];
        #pragma unroll
        for (int i = 0; i < 18; ++i) z += wr[i] * pe[i];
        Zrow[t * 64 + j] = SIN_SCALE * z;
    } else {
        int c = t - 1024;
        const float* pe = ec + (long)c * 18;          // point (r=0, c)
        float z = 0.f;
        #pragma unroll
        for (int i = 0; i < 18; ++i) z += wr[i] * (pe[i] - ec[i]);
        Zcol[c * 64 + j] = SIN_SCALE * z;
    }
}

// ---------------- stage 1: [x cast -> bf16] || [generate W via MFMA] ----------
// 9216 blocks; blockIdx.x % 9 == 0 -> siren block (1024 of them), else cast
// block (8192). Interleaving keeps every CU fed with both HBM-bound (cast)
// and compute-bound (siren) waves so the two phases overlap.
//
// siren: wave covers 256 consecutive points of one row: 8 iters x 2
// interleaved 16-pt tiles. A-frag: m=ln (point), k=kq*8+j (+32 for *1).
// B-frag: n=nt*16+ln. C/D: col=ln (=n), row=kq*4+rg (=point) [m89/m91].
__global__ __launch_bounds__(256, 3) void fused_cast_siren(
        const float4* __restrict__ x, unsigned short* __restrict__ xb,
        const float* __restrict__ Zrow, const float* __restrict__ Zcol,
        const float* __restrict__ W2, const float* __restrict__ b2,
        const float* __restrict__ W3, const float* __restrict__ b3,
        unsigned short* __restrict__ Wout) {
    int bid = blockIdx.x;
    int sb  = bid / 9;
    if (bid - sb * 9 != 0) {
        // ---- cast path: one float4 -> ushort4 per thread ----
        int cb = bid - sb - 1;                       // 0..8191
        long i = (long)cb * 256 + threadIdx.x;
        float4 v = x[i];
        ushort4 o;
        o.x = f2bf(v.x); o.y = f2bf(v.y); o.z = f2bf(v.z); o.w = f2bf(v.w);
        *(ushort4*)(xb + i * 4) = o;
        return;
    }

    // ---- siren path ----
    int lane = threadIdx.x & 63;
    int wv   = threadIdx.x >> 6;
    int ln   = lane & 15;
    int kq   = lane >> 4;

    // Preload B-frags of S*W2 (trunc bf16), S*b2, W3
    bf16x8 bfrag[2][4];
    #pragma unroll
    for (int kc = 0; kc < 2; ++kc)
        #pragma unroll
        for (int nt = 0; nt < 4; ++nt) {
            const float* src = W2 + (nt * 16 + ln) * 64 + kc * 32 + kq * 8;
            union { bf16x8 v; unsigned u[4]; } tmp;
            #pragma unroll
            for (int q = 0; q < 4; ++q)
                tmp.u[q] = pktrunc(SIN_SCALE * src[2*q], SIN_SCALE * src[2*q + 1]);
            bfrag[kc][nt] = tmp.v;
        }
    float b2v[4], w3v[4];
    #pragma unroll
    for (int nt = 0; nt < 4; ++nt) {
        b2v[nt] = SIN_SCALE * b2[nt * 16 + ln];
        w3v[nt] = W3[nt * 16 + ln];
    }
    float b3s = b3[0];

    int wid = sb * 4 + wv;                  // 0..4095 waves
    int r   = wid >> 2;                     // 4 waves per row
    int c0  = (wid & 3) * 256;

    // wave-invariant Zrow fragment (k = kq*8+j and 32+kq*8+j)
    const float* zrp = Zrow + (long)r * 64 + kq * 8;
    float zr0[8], zr1[8];
    #pragma unroll
    for (int j = 0; j < 8; ++j) { zr0[j] = zrp[j]; zr1[j] = zrp[32 + j]; }

    for (int it = 0; it < 8; ++it) {
        int ca = c0 + it * 32 + ln;                 // tile A point col
        const float* zca = Zcol + (long)ca * 64 + kq * 8;
        const float* zcb = zca + 16 * 64;           // tile B: +16 cols

        float sa0[8], sa1[8], sb0[8], sb1[8];
        #pragma unroll
        for (int j = 0; j < 8; ++j) {
            sa0[j] = sinrev(zr0[j] + zca[j]);
            sa1[j] = sinrev(zr1[j] + zca[32 + j]);
            sb0[j] = sinrev(zr0[j] + zcb[j]);
            sb1[j] = sinrev(zr1[j] + zcb[32 + j]);
        }
        union { bf16x8 v; unsigned u[4]; } a0, a1, bb0, bb1;
        #pragma unroll
        for (int q = 0; q < 4; ++q) {
            a0.u[q]  = pktrunc(sa0[2*q], sa0[2*q + 1]);
            a1.u[q]  = pktrunc(sa1[2*q], sa1[2*q + 1]);
            bb0.u[q] = pktrunc(sb0[2*q], sb0[2*q + 1]);
            bb1.u[q] = pktrunc(sb1[2*q], sb1[2*q + 1]);
        }

        f32x4 acca[4] = {}, accb[4] = {};
        #pragma unroll
        for (int nt = 0; nt < 4; ++nt) {
            acca[nt] = __builtin_amdgcn_mfma_f32_16x16x32_bf16(a0.v,  bfrag[0][nt], acca[nt], 0, 0, 0);
            accb[nt] = __builtin_amdgcn_mfma_f32_16x16x32_bf16(bb0.v, bfrag[0][nt], accb[nt], 0, 0, 0);
            acca[nt] = __builtin_amdgcn_mfma_f32_16x16x32_bf16(a1.v,  bfrag[1][nt], acca[nt], 0, 0, 0);
            accb[nt] = __builtin_amdgcn_mfma_f32_16x16x32_bf16(bb1.v, bfrag[1][nt], accb[nt], 0, 0, 0);
        }

        float pa[4], pb[4];
        #pragma unroll
        for (int rg = 0; rg < 4; ++rg) {
            float s = 0.f, t2 = 0.f;
            #pragma unroll
            for (int nt = 0; nt < 4; ++nt) {
                s  += w3v[nt] * sinrev(acca[nt][rg] + b2v[nt]);
                t2 += w3v[nt] * sinrev(accb[nt][rg] + b2v[nt]);
            }
            pa[rg] = s; pb[rg] = t2;
        }
        #pragma unroll
        for (int rg = 0; rg < 4; ++rg) {
            pa[rg] = swz_add<0x041F>(pa[rg]);  pb[rg] = swz_add<0x041F>(pb[rg]);
            pa[rg] = swz_add<0x081F>(pa[rg]);  pb[rg] = swz_add<0x081F>(pb[rg]);
            pa[rg] = swz_add<0x101F>(pa[rg]);  pb[rg] = swz_add<0x101F>(pb[rg]);
            pa[rg] = swz_add<0x201F>(pa[rg]);  pb[rg] = swz_add<0x201F>(pb[rg]);
        }

        if (ln == 0) {                       // 4 lanes store 4 points per tile (RNE)
            long p0 = (long)r * 1024 + c0 + it * 32;
            ushort4 oa, ob;
            oa.x = f2bf(pa[0] + b3s); oa.y = f2bf(pa[1] + b3s);
            oa.z = f2bf(pa[2] + b3s); oa.w = f2bf(pa[3] + b3s);
            ob.x = f2bf(pb[0] + b3s); ob.y = f2bf(pb[1] + b3s);
            ob.z = f2bf(pb[2] + b3s); ob.w = f2bf(pb[3] + b3s);
            *(ushort4*)(Wout + p0 + kq * 4)      = oa;
            *(ushort4*)(Wout + p0 + 16 + kq * 4) = ob;
        }
    }
}

// ---------------- stage 2: out = x @ W^T + bias (bf16 MFMA) ----------------
// A = x_bf16 [8192][1024] K-contig; B = W_bf16 [1024][1024] (n=r, k=c) K-contig.
// Block: 256 thr = 4 waves (2x2 of 64x64), tile 128x128, BK=64.
// DOUBLE-BUFFERED: prefetch tile t+1 (global_load_lds) before computing tile
// t; single __syncthreads per tile (its implicit vmcnt(0) drain lands AFTER
// 32 MFMAs, so the ~500cy load latency is hidden). LDS 64KB -> 2 blocks/CU,
// exactly matching the 512-block grid.
// Row = 128 B = 8 chunks of 16 B; stored position p holds logical chunk
// p ^ (row&7) (staging fetches the matching global chunk; m104-legal since
// LDS dest stays linear in lane). Fragment reads hit all 8 positions ->
// 2 lanes/bank = free (m136).
__global__ __launch_bounds__(256) void gemm_kernel(
        const unsigned short* __restrict__ A,
        const unsigned short* __restrict__ B,
        const float* __restrict__ bias,
        float* __restrict__ C) {
    const int K = 1024;
    __shared__ __align__(16) unsigned short As[2][128 * 64];
    __shared__ __align__(16) unsigned short Bs[2][128 * 64];

    int tid  = threadIdx.x;
    int lane = tid & 63;
    int wv   = tid >> 6;
    int wm   = wv & 1, wn = wv >> 1;
    long Abase = (long)blockIdx.x * 128 * K;
    long Bbase = (long)blockIdx.y * 128 * K;

    int sr8 = tid >> 3;     // staging row 0..31 (+32q)
    int sl  = tid & 7;      // staging chunk slot
    int rsel = lane & 15;   // fragment m/n within 16
    int kq   = lane >> 4;   // fragment k-quad 0..3

    f32x4 acc[4][4] = {};

    // stage one 128x64 A-tile + B-tile into buffer sbuf
    auto stage = [&](int kt, int sbuf) {
        #pragma unroll
        for (int q = 0; q < 4; ++q) {
            int row = q * 32 + sr8;
            int cc  = sl ^ (row & 7);                        // global chunk to fetch
            const unsigned short* ga = A + Abase + (long)row * K + kt + cc * 8;
            const unsigned short* gb = B + Bbase + (long)row * K + kt + cc * 8;
            unsigned short* la = &As[sbuf][(q * 256 + wv * 64) * 8];  // wave-uniform base
            unsigned short* lb = &Bs[sbuf][(q * 256 + wv * 64) * 8];
            async_ld16(ga, la);
            async_ld16(gb, lb);
        }
    };

    auto compute = [&](int sbuf) {
        #pragma unroll
        for (int h = 0; h < 2; ++h) {
            bf16x8 af[4], bf[4];
            #pragma unroll
            for (int mi = 0; mi < 4; ++mi) {
                int row = wm * 64 + mi * 16 + rsel;
                int ch  = (h * 4 + kq) ^ (row & 7);
                af[mi] = *(const bf16x8*)&As[sbuf][row * 64 + ch * 8];
            }
            #pragma unroll
            for (int ni = 0; ni < 4; ++ni) {
                int row = wn * 64 + ni * 16 + rsel;
                int ch  = (h * 4 + kq) ^ (row & 7);
                bf[ni] = *(const bf16x8*)&Bs[sbuf][row * 64 + ch * 8];
            }
            #pragma unroll
            for (int mi = 0; mi < 4; ++mi)
                #pragma unroll
                for (int ni = 0; ni < 4; ++ni)
                    acc[mi][ni] = __builtin_amdgcn_mfma_f32_16x16x32_bf16(
                        af[mi], bf[ni], acc[mi][ni], 0, 0, 0);
        }
    };

    stage(0, 0);
    __syncthreads();                 // drain prologue loads
    int buf = 0;
    for (int kt = 64; kt < K; kt += 64) {
        stage(kt, buf ^ 1);          // prefetch next tile (in flight across MFMAs)
        compute(buf);
        __syncthreads();             // all ds_reads of buf done + prefetch landed
        buf ^= 1;
    }
    compute(buf);                    // last tile, no further staging

    // epilogue: C/D layout col=lane&15, row=(lane>>4)*4+reg  (m89/m91 verified)
    int row0 = blockIdx.x * 128 + wm * 64;
    int col0 = blockIdx.y * 128 + wn * 64;
    #pragma unroll
    for (int ni = 0; ni < 4; ++ni) {
        int col = col0 + ni * 16 + rsel;
        float bv = bias[col];
        #pragma unroll
        for (int mi = 0; mi < 4; ++mi) {
            int rbase = row0 + mi * 16 + kq * 4;
            #pragma unroll
            for (int r = 0; r < 4; ++r)
                C[(long)(rbase + r) * 1024 + col] = acc[mi][ni][r] + bv;
        }
    }
}

extern "C" void kernel_launch(void* const* d_in, const int* in_sizes, int n_in,
                              void* d_out, int out_size, void* d_ws, size_t ws_size,
                              hipStream_t stream) {
    const float* x    = (const float*)d_in[0];
    const float* ec   = (const float*)d_in[1];
    const float* W1   = (const float*)d_in[2];
    const float* b1   = (const float*)d_in[3];
    const float* W2   = (const float*)d_in[4];
    const float* b2   = (const float*)d_in[5];
    const float* W3   = (const float*)d_in[6];
    const float* b3   = (const float*)d_in[7];
    const float* bias = (const float*)d_in[8];
    float* out = (float*)d_out;

    unsigned short* xb = (unsigned short*)d_ws;            // 8192*1024 bf16 = 16 MB
    unsigned short* Wb = xb + (size_t)8192 * 1024;         // 1024*1024 bf16 = 2 MB
    float* Zrow = (float*)(Wb + (size_t)1024 * 1024);      // 1024*64 f32 = 256 KB
    float* Zcol = Zrow + 1024 * 64;                        // 1024*64 f32 = 256 KB

    tables_kernel<<<512, 256, 0, stream>>>(ec, W1, b1, Zrow, Zcol);
    fused_cast_siren<<<9216, 256, 0, stream>>>((const float4*)x, xb, Zrow, Zcol,
                                               W2, b2, W3, b3, Wb);
    dim3 g(64, 8);
    gemm_kernel<<<g, 256, 0, stream>>>(xb, Wb, bias, out);
}

// Round 2
// 212.169 us; speedup vs baseline: 1.0135x; 1.0135x over previous
//
#include <hip/hip_runtime.h>
#include <hip/hip_bf16.h>

// SirenLinear: out[b,r] = sum_c x[b,c] * W[r,c] + bias[r]
//   W[r,c] = b3 + h2 . W3,  h2 = sin(30*(W2 h1 + b2)),  h1 = sin(30*(W1 e + b1))
//
// Round-8 changes (from rocprof: fused_cast_siren 67us, VALUBusy 25%,
// MfmaUtil 4.7%, Occupancy 24% -- latency-bound, only 4 siren waves/SIMD):
//  * siren work split 2x finer: 4 iters/wave instead of 8 -> 2048 siren
//    blocks = 8 blocks/CU = 32 waves/CU (full occupancy at VGPR<=64).
//    TLP now covers the load->sin->mfma->sin->swizzle dependency chain.
//  * cast blocks do 2 float4/thread (4096 blocks) -> better per-block MLP,
//    fewer dispatches. Interleave 1 siren per 3 blocks (grid 6144).
//  * gemm keeps round-7 double-buffered LDS (1 barrier/K-tile).

typedef __attribute__((ext_vector_type(8))) short bf16x8;
typedef __attribute__((ext_vector_type(4))) float f32x4;

#define SIN_SCALE 4.77464829275686f   // 30 / (2*pi)

__device__ __forceinline__ unsigned short f2bf(float f) {
    union { float f; unsigned u; } v; v.f = f;
    unsigned r = v.u + 0x7fffu + ((v.u >> 16) & 1u);   // RNE
    return (unsigned short)(r >> 16);
}

// pack 2 floats -> 2 bf16 by truncation (cheap; RNE kept for final store)
__device__ __forceinline__ unsigned pktrunc(float a, float b) {
    union { float f; unsigned u; } x, y; x.f = a; y.f = b;
    return (x.u >> 16) | (y.u & 0xffff0000u);
}

// sin(2*pi*x) -- raw v_sin_f32, valid |x| <= 256 revs (here |x| <= ~8.3)
__device__ __forceinline__ float sinrev(float x) {
    return __builtin_amdgcn_sinf(x);
}

// butterfly add over lane^m (bitmode ds_swizzle)
template <int OFF>
__device__ __forceinline__ float swz_add(float v) {
    return v + __int_as_float(__builtin_amdgcn_ds_swizzle(__float_as_int(v), OFF));
}

__device__ __forceinline__ void async_ld16(const void* g, void* l) {
    __builtin_amdgcn_global_load_lds(
        (__attribute__((address_space(1))) void*)g,
        (__attribute__((address_space(3))) void*)l, 16, 0, 0);
}

// ---------------- stage 0: layer-1 separable tables ----------------
// Zrow[r][j] = S*(W1[j,:].e(r,0)+b1[j]);  Zcol[c][j] = S*(W1[j,:].(e(0,c)-e(0,0)))
__global__ __launch_bounds__(256) void tables_kernel(
        const float* __restrict__ ec,
        const float* __restrict__ W1, const float* __restrict__ b1,
        float* __restrict__ Zrow, float* __restrict__ Zcol) {
    int idx = blockIdx.x * 256 + threadIdx.x;    // 0..131071
    int j = idx & 63;
    int t = idx >> 6;                            // 0..2047
    const float* wr = W1 + j * 18;
    if (t < 1024) {
        const float* pe = ec + (long)t * 1024 * 18;   // point (r=t, c=0)
        float z = b1[j];
        #pragma unroll
        for (int i = 0; i < 18; ++i) z += wr[i] * pe[i];
        Zrow[t * 64 + j] = SIN_SCALE * z;
    } else {
        int c = t - 1024;
        const float* pe = ec + (long)c * 18;          // point (r=0, c)
        float z = 0.f;
        #pragma unroll
        for (int i = 0; i < 18; ++i) z += wr[i] * (pe[i] - ec[i]);
        Zcol[c * 64 + j] = SIN_SCALE * z;
    }
}

// ---------------- stage 1: [x cast -> bf16] || [generate W via MFMA] ----------
// 6144 blocks; blockIdx.x % 3 == 0 -> siren block (2048 of them), else cast
// block (4096, 2 float4/thread). Interleaving keeps every CU fed with both
// HBM-bound (cast) and compute-bound (siren) waves (m114 overlap).
//
// siren: wave covers 128 consecutive points of one row: 4 iters x 2
// interleaved 16-pt tiles. A-frag: m=ln (point), k=kq*8+j (+32 for *1).
// B-frag: n=nt*16+ln. C/D: col=ln (=n), row=kq*4+rg (=point) [m89/m91].
// 2048 siren blocks = 8 blocks/CU resident (VGPR~60 -> 8 waves/SIMD).
__global__ __launch_bounds__(256, 3) void fused_cast_siren(
        const float4* __restrict__ x, unsigned short* __restrict__ xb,
        const float* __restrict__ Zrow, const float* __restrict__ Zcol,
        const float* __restrict__ W2, const float* __restrict__ b2,
        const float* __restrict__ W3, const float* __restrict__ b3,
        unsigned short* __restrict__ Wout) {
    int bid = blockIdx.x;
    int sb  = bid / 3;
    if (bid - sb * 3 != 0) {
        // ---- cast path: two float4 -> ushort4 per thread ----
        int cb = bid - sb - 1;                       // 0..4095
        long i = (long)cb * 512 + threadIdx.x;
        float4 v0 = x[i];
        float4 v1 = x[i + 256];
        ushort4 o0, o1;
        o0.x = f2bf(v0.x); o0.y = f2bf(v0.y); o0.z = f2bf(v0.z); o0.w = f2bf(v0.w);
        o1.x = f2bf(v1.x); o1.y = f2bf(v1.y); o1.z = f2bf(v1.z); o1.w = f2bf(v1.w);
        *(ushort4*)(xb + i * 4)         = o0;
        *(ushort4*)(xb + (i + 256) * 4) = o1;
        return;
    }

    // ---- siren path: sb in 0..2047 ----
    int lane = threadIdx.x & 63;
    int wv   = threadIdx.x >> 6;
    int ln   = lane & 15;
    int kq   = lane >> 4;

    // Preload B-frags of S*W2 (trunc bf16), S*b2, W3
    bf16x8 bfrag[2][4];
    #pragma unroll
    for (int kc = 0; kc < 2; ++kc)
        #pragma unroll
        for (int nt = 0; nt < 4; ++nt) {
            const float* src = W2 + (nt * 16 + ln) * 64 + kc * 32 + kq * 8;
            union { bf16x8 v; unsigned u[4]; } tmp;
            #pragma unroll
            for (int q = 0; q < 4; ++q)
                tmp.u[q] = pktrunc(SIN_SCALE * src[2*q], SIN_SCALE * src[2*q + 1]);
            bfrag[kc][nt] = tmp.v;
        }
    float b2v[4], w3v[4];
    #pragma unroll
    for (int nt = 0; nt < 4; ++nt) {
        b2v[nt] = SIN_SCALE * b2[nt * 16 + ln];
        w3v[nt] = W3[nt * 16 + ln];
    }
    float b3s = b3[0];

    int wid = sb * 4 + wv;                  // 0..8191 waves
    int r   = wid >> 3;                     // 8 waves per row
    int c0  = (wid & 7) * 128;

    // wave-invariant Zrow fragment (k = kq*8+j and 32+kq*8+j)
    const float* zrp = Zrow + (long)r * 64 + kq * 8;
    float zr0[8], zr1[8];
    #pragma unroll
    for (int j = 0; j < 8; ++j) { zr0[j] = zrp[j]; zr1[j] = zrp[32 + j]; }

    for (int it = 0; it < 4; ++it) {
        int ca = c0 + it * 32 + ln;                 // tile A point col
        const float* zca = Zcol + (long)ca * 64 + kq * 8;
        const float* zcb = zca + 16 * 64;           // tile B: +16 cols

        float sa0[8], sa1[8], sb0[8], sb1[8];
        #pragma unroll
        for (int j = 0; j < 8; ++j) {
            sa0[j] = sinrev(zr0[j] + zca[j]);
            sa1[j] = sinrev(zr1[j] + zca[32 + j]);
            sb0[j] = sinrev(zr0[j] + zcb[j]);
            sb1[j] = sinrev(zr1[j] + zcb[32 + j]);
        }
        union { bf16x8 v; unsigned u[4]; } a0, a1, bb0, bb1;
        #pragma unroll
        for (int q = 0; q < 4; ++q) {
            a0.u[q]  = pktrunc(sa0[2*q], sa0[2*q + 1]);
            a1.u[q]  = pktrunc(sa1[2*q], sa1[2*q + 1]);
            bb0.u[q] = pktrunc(sb0[2*q], sb0[2*q + 1]);
            bb1.u[q] = pktrunc(sb1[2*q], sb1[2*q + 1]);
        }

        f32x4 acca[4] = {}, accb[4] = {};
        #pragma unroll
        for (int nt = 0; nt < 4; ++nt) {
            acca[nt] = __builtin_amdgcn_mfma_f32_16x16x32_bf16(a0.v,  bfrag[0][nt], acca[nt], 0, 0, 0);
            accb[nt] = __builtin_amdgcn_mfma_f32_16x16x32_bf16(bb0.v, bfrag[0][nt], accb[nt], 0, 0, 0);
            acca[nt] = __builtin_amdgcn_mfma_f32_16x16x32_bf16(a1.v,  bfrag[1][nt], acca[nt], 0, 0, 0);
            accb[nt] = __builtin_amdgcn_mfma_f32_16x16x32_bf16(bb1.v, bfrag[1][nt], accb[nt], 0, 0, 0);
        }

        float pa[4], pb[4];
        #pragma unroll
        for (int rg = 0; rg < 4; ++rg) {
            float s = 0.f, t2 = 0.f;
            #pragma unroll
            for (int nt = 0; nt < 4; ++nt) {
                s  += w3v[nt] * sinrev(acca[nt][rg] + b2v[nt]);
                t2 += w3v[nt] * sinrev(accb[nt][rg] + b2v[nt]);
            }
            pa[rg] = s; pb[rg] = t2;
        }
        #pragma unroll
        for (int rg = 0; rg < 4; ++rg) {
            pa[rg] = swz_add<0x041F>(pa[rg]);  pb[rg] = swz_add<0x041F>(pb[rg]);
            pa[rg] = swz_add<0x081F>(pa[rg]);  pb[rg] = swz_add<0x081F>(pb[rg]);
            pa[rg] = swz_add<0x101F>(pa[rg]);  pb[rg] = swz_add<0x101F>(pb[rg]);
            pa[rg] = swz_add<0x201F>(pa[rg]);  pb[rg] = swz_add<0x201F>(pb[rg]);
        }

        if (ln == 0) {                       // 4 lanes store 4 points per tile (RNE)
            long p0 = (long)r * 1024 + c0 + it * 32;
            ushort4 oa, ob;
            oa.x = f2bf(pa[0] + b3s); oa.y = f2bf(pa[1] + b3s);
            oa.z = f2bf(pa[2] + b3s); oa.w = f2bf(pa[3] + b3s);
            ob.x = f2bf(pb[0] + b3s); ob.y = f2bf(pb[1] + b3s);
            ob.z = f2bf(pb[2] + b3s); ob.w = f2bf(pb[3] + b3s);
            *(ushort4*)(Wout + p0 + kq * 4)      = oa;
            *(ushort4*)(Wout + p0 + 16 + kq * 4) = ob;
        }
    }
}

// ---------------- stage 2: out = x @ W^T + bias (bf16 MFMA) ----------------
// A = x_bf16 [8192][1024] K-contig; B = W_bf16 [1024][1024] (n=r, k=c) K-contig.
// Block: 256 thr = 4 waves (2x2 of 64x64), tile 128x128, BK=64.
// DOUBLE-BUFFERED: prefetch tile t+1 (global_load_lds) before computing tile
// t; single __syncthreads per tile (its implicit vmcnt(0) drain lands AFTER
// 32 MFMAs, so the ~500cy load latency is hidden). LDS 64KB -> 2 blocks/CU,
// exactly matching the 512-block grid.
// Row = 128 B = 8 chunks of 16 B; stored position p holds logical chunk
// p ^ (row&7) (staging fetches the matching global chunk; m104-legal since
// LDS dest stays linear in lane). Fragment reads hit all 8 positions ->
// 2 lanes/bank = free (m136).
__global__ __launch_bounds__(256) void gemm_kernel(
        const unsigned short* __restrict__ A,
        const unsigned short* __restrict__ B,
        const float* __restrict__ bias,
        float* __restrict__ C) {
    const int K = 1024;
    __shared__ __align__(16) unsigned short As[2][128 * 64];
    __shared__ __align__(16) unsigned short Bs[2][128 * 64];

    int tid  = threadIdx.x;
    int lane = tid & 63;
    int wv   = tid >> 6;
    int wm   = wv & 1, wn = wv >> 1;
    long Abase = (long)blockIdx.x * 128 * K;
    long Bbase = (long)blockIdx.y * 128 * K;

    int sr8 = tid >> 3;     // staging row 0..31 (+32q)
    int sl  = tid & 7;      // staging chunk slot
    int rsel = lane & 15;   // fragment m/n within 16
    int kq   = lane >> 4;   // fragment k-quad 0..3

    f32x4 acc[4][4] = {};

    // stage one 128x64 A-tile + B-tile into buffer sbuf
    auto stage = [&](int kt, int sbuf) {
        #pragma unroll
        for (int q = 0; q < 4; ++q) {
            int row = q * 32 + sr8;
            int cc  = sl ^ (row & 7);                        // global chunk to fetch
            const unsigned short* ga = A + Abase + (long)row * K + kt + cc * 8;
            const unsigned short* gb = B + Bbase + (long)row * K + kt + cc * 8;
            unsigned short* la = &As[sbuf][(q * 256 + wv * 64) * 8];  // wave-uniform base
            unsigned short* lb = &Bs[sbuf][(q * 256 + wv * 64) * 8];
            async_ld16(ga, la);
            async_ld16(gb, lb);
        }
    };

    auto compute = [&](int sbuf) {
        #pragma unroll
        for (int h = 0; h < 2; ++h) {
            bf16x8 af[4], bf[4];
            #pragma unroll
            for (int mi = 0; mi < 4; ++mi) {
                int row = wm * 64 + mi * 16 + rsel;
                int ch  = (h * 4 + kq) ^ (row & 7);
                af[mi] = *(const bf16x8*)&As[sbuf][row * 64 + ch * 8];
            }
            #pragma unroll
            for (int ni = 0; ni < 4; ++ni) {
                int row = wn * 64 + ni * 16 + rsel;
                int ch  = (h * 4 + kq) ^ (row & 7);
                bf[ni] = *(const bf16x8*)&Bs[sbuf][row * 64 + ch * 8];
            }
            #pragma unroll
            for (int mi = 0; mi < 4; ++mi)
                #pragma unroll
                for (int ni = 0; ni < 4; ++ni)
                    acc[mi][ni] = __builtin_amdgcn_mfma_f32_16x16x32_bf16(
                        af[mi], bf[ni], acc[mi][ni], 0, 0, 0);
        }
    };

    stage(0, 0);
    __syncthreads();                 // drain prologue loads
    int buf = 0;
    for (int kt = 64; kt < K; kt += 64) {
        stage(kt, buf ^ 1);          // prefetch next tile (in flight across MFMAs)
        compute(buf);
        __syncthreads();             // all ds_reads of buf done + prefetch landed
        buf ^= 1;
    }
    compute(buf);                    // last tile, no further staging

    // epilogue: C/D layout col=lane&15, row=(lane>>4)*4+reg  (m89/m91 verified)
    int row0 = blockIdx.x * 128 + wm * 64;
    int col0 = blockIdx.y * 128 + wn * 64;
    #pragma unroll
    for (int ni = 0; ni < 4; ++ni) {
        int col = col0 + ni * 16 + rsel;
        float bv = bias[col];
        #pragma unroll
        for (int mi = 0; mi < 4; ++mi) {
            int rbase = row0 + mi * 16 + kq * 4;
            #pragma unroll
            for (int r = 0; r < 4; ++r)
                C[(long)(rbase + r) * 1024 + col] = acc[mi][ni][r] + bv;
        }
    }
}

extern "C" void kernel_launch(void* const* d_in, const int* in_sizes, int n_in,
                              void* d_out, int out_size, void* d_ws, size_t ws_size,
                              hipStream_t stream) {
    const float* x    = (const float*)d_in[0];
    const float* ec   = (const float*)d_in[1];
    const float* W1   = (const float*)d_in[2];
    const float* b1   = (const float*)d_in[3];
    const float* W2   = (const float*)d_in[4];
    const float* b2   = (const float*)d_in[5];
    const float* W3   = (const float*)d_in[6];
    const float* b3   = (const float*)d_in[7];
    const float* bias = (const float*)d_in[8];
    float* out = (float*)d_out;

    unsigned short* xb = (unsigned short*)d_ws;            // 8192*1024 bf16 = 16 MB
    unsigned short* Wb = xb + (size_t)8192 * 1024;         // 1024*1024 bf16 = 2 MB
    float* Zrow = (float*)(Wb + (size_t)1024 * 1024);      // 1024*64 f32 = 256 KB
    float* Zcol = Zrow + 1024 * 64;                        // 1024*64 f32 = 256 KB

    tables_kernel<<<512, 256, 0, stream>>>(ec, W1, b1, Zrow, Zcol);
    fused_cast_siren<<<6144, 256, 0, stream>>>((const float4*)x, xb, Zrow, Zcol,
                                               W2, b2, W3, b3, Wb);
    dim3 g(64, 8);
    gemm_kernel<<<g, 256, 0, stream>>>(xb, Wb, bias, out);
}